// Round 10
// baseline (1279.912 us; speedup 1.0000x reference)
//
#include <hip/hip_runtime.h>

typedef float f32x4 __attribute__((ext_vector_type(4)));
typedef short s16x8 __attribute__((ext_vector_type(8)));
typedef unsigned uint4v __attribute__((ext_vector_type(4)));

#define HH   768
#define HHP  776   // h-buffer row pitch in shorts (GLOBAL and LDS identical)
#define SS   256
#define GR   8     // row groups (16 rows each); g = blockIdx & 7
#define GP   24    // col blocks per group; p = blockIdx >> 3
#define NROW 128
#define LDP  776   // LDS row pitch (shorts); 1552B = 16B-aligned rows
#define PP   68    // partials row pitch (floats)

__device__ __forceinline__ unsigned short f2bf(float f) {
  unsigned int u = __float_as_uint(f);
  u += 0x7FFFu + ((u >> 16) & 1u);          // RTNE
  return (unsigned short)(u >> 16);
}
__device__ __forceinline__ float bf2f(unsigned short s) {
  return __uint_as_float(((unsigned int)s) << 16);
}
__device__ __forceinline__ float sigm(float v) { return 1.0f / (1.0f + __expf(-v)); }
__device__ __forceinline__ float tanhf_(float v) {
  return 1.0f - 2.0f / (__expf(2.0f * v) + 1.0f);
}
// async global->LDS, 16B per lane; dest = wave-uniform base + lane*16 (HW).
__device__ __forceinline__ void gll16(const void* gp, void* lp) {
  __builtin_amdgcn_global_load_lds(
      (const __attribute__((address_space(1))) unsigned*)gp,
      (__attribute__((address_space(3))) unsigned*)lp, 16, 0, 0);
}

// 192 blocks x 512 threads (8 waves, 2/SIMD via launch_bounds(512,2)).
// Static roles: g = blockIdx&7 (rows [16g,16g+16)), p = blockIdx>>3 (hidden
// cols [32p,32p+32)); gate cols permuted col = hcol*4 + gate.
// Wave w: colh = w&1 (64-gate-col half), ks = w>>1 (6-kt slice of K).
// R12 (WIN 968->830): h transported bf16-only. R14 (neutral, kept): staging
// via global_load_lds w=16, pitch-776 identity copy. R15 (WIN 830->687,
// steady 624): W single-bf16 (Blo dropped) — 24 MFMA/wave. R16 (neutral,
// kept): bias/x-weight + c-state hoisted to registers.
// R17 (this round): PER-WAVE distributed step barrier. Coherence ops are
// R6-proven byte-for-byte (agent fetch_add arrival, agent relaxed-load
// poll); only the STRUCTURE changes:
//   wave epilogue -> s_waitcnt vmcnt(0) (own stores only) -> lane0
//   ds_add_rtn on a monotonic LDS counter -> the wave seeing old==8*bars-1
//   (all 8 waves arrived, each post-drain) issues the ONE global arrival
//   (still 24 RMWs/step — no R13 RMW-poll contention) -> EVERY wave polls
//   the global counter itself and self-releases into staging.
// Deletes gbar's two __syncthreads + block-wide waitcnt(0) per step (2
// syncs/step remain: post-staging, post-partials); early waves overlap
// arrival with slow waves' epilogues. Visibility identical to R6: LDS
// count==8 => every wave's vmcnt(0) preceded its ds_add (program order).
// No intra-block hazard: epilogue reads part; staging writes lds_hi; the
// post-staging sync re-aligns before GEMM reads.
// Closed dead ends (do not revisit): R8 flag-poll, R9 sc0-load poll (hang),
// R13 local RMW-poll (+60us), R10 direct-L2 A-frags (-32%), R11 split-phase
// staging (-18%), wave-per-n-tile restructure (rejected on paper).
__global__ void __launch_bounds__(512, 2) lstm_persistent(
    const float* __restrict__ xin, const float* __restrict__ h0,
    const float* __restrict__ c0,
    const float* __restrict__ Wi, const float* __restrict__ bi,
    const float* __restrict__ Wf, const float* __restrict__ bfv,
    const float* __restrict__ Wc, const float* __restrict__ bc,
    const float* __restrict__ Wo, const float* __restrict__ bo,
    const float* __restrict__ Wout, const float* __restrict__ bout,
    float* __restrict__ out,
    unsigned short* __restrict__ hhi0, unsigned short* __restrict__ hhi1,
    unsigned short* __restrict__ hhi2,
    unsigned short* __restrict__ hlo0, unsigned short* __restrict__ hlo1,
    unsigned short* __restrict__ hlo2,
    unsigned* __restrict__ bar)
{
  const int tid = threadIdx.x, wave = tid >> 6, lane = tid & 63;
  const int l15 = lane & 15, quad = lane >> 4;
  const int g = blockIdx.x & 7, p = blockIdx.x >> 3;
  const int row_base = g * 16, hcol_base = p * 32;
  const int colh = wave & 1, ks = wave >> 1;   // col-half / kt-slice

  __shared__ __align__(16) unsigned short lds_hi[16 * LDP];
  __shared__ __align__(16) float part[2][4][16][PP];   // [colh][ks][row][col64]
  __shared__ float bw_b[128], bw_w[128];               // bias / x-weight per col
  __shared__ float c_lds[16][33];                      // init handoff only
  __shared__ float x_lds[16];
  __shared__ unsigned lds_ctr;                         // monotonic wave arrivals
  __shared__ int s_fast;

  unsigned* ctr = bar + g * 64;              // step barrier (256B-spaced)
  unsigned* rdy = bar + 512 + g * 16;        // rendezvous counter
  unsigned* ids = bar + 640 + g * 32;        // 24 published XCC_IDs

  // ---- one-time vote (tid0): all 24 members on one XCD? [R6-proven] ----
  if (tid == 0) {
    lds_ctr = 0;
    const unsigned my = (__builtin_amdgcn_s_getreg(20 | (3 << 11)) & 15u) + 1u;
    __hip_atomic_store(ids + p, my, __ATOMIC_RELAXED, __HIP_MEMORY_SCOPE_AGENT);
    __hip_atomic_fetch_add(rdy, 1u, __ATOMIC_RELEASE, __HIP_MEMORY_SCOPE_AGENT);
    while (__hip_atomic_load(rdy, __ATOMIC_ACQUIRE, __HIP_MEMORY_SCOPE_AGENT)
           < (unsigned)GP)
      __builtin_amdgcn_s_sleep(8);
    int ok = 1;
    for (int q = 0; q < GP; ++q)
      ok &= (__hip_atomic_load(ids + q, __ATOMIC_RELAXED,
                               __HIP_MEMORY_SCOPE_AGENT) == my);
    s_fast = ok;
  }

  // ---- one-time: weights -> bf16 hi B-fragments (n=lane&15, k=quad*8+j) --
  s16x8 Bhi[6][4];
#pragma unroll
  for (int n = 0; n < 4; ++n) {
    const int col = p * 128 + colh * 64 + n * 16 + l15;  // permuted gate col
    const int gg = col & 3, hc = col >> 2;
    const float* W = (gg == 0) ? Wi : (gg == 1) ? Wf : (gg == 2) ? Wc : Wo;
#pragma unroll
    for (int ktl = 0; ktl < 6; ++ktl) {
      const int kt = ks * 6 + ktl;
      s16x8 vh;
#pragma unroll
      for (int j = 0; j < 8; ++j) {
        const int k = kt * 32 + quad * 8 + j;
        vh[j] = (short)f2bf(W[(1 + k) * HH + hc]);
      }
      Bhi[ktl][n] = vh;
    }
  }

  // ---- one-time: bias + x-weight tables -> LDS (per permuted gate col) ----
  if (tid < 128) {
    const int gg = tid & 3;
    const int hc = p * 32 + (tid >> 2);
    const float* W  = (gg == 0) ? Wi : (gg == 1) ? Wf : (gg == 2) ? Wc : Wo;
    const float* bb = (gg == 0) ? bi : (gg == 1) ? bfv : (gg == 2) ? bc : bo;
    bw_b[tid] = bb[hc];
    bw_w[tid] = W[hc];                       // W row 0 = x weight (exact fp32)
  }

  // ---- init: c->LDS; h0 -> parity-0 hi buffer (agent stores, pitch 776) --
  if (tid < 256) {
    const int lr = tid >> 4, lc = (tid & 15) * 2;
    const int gidx = (row_base + lr) * HH + hcol_base + lc;    // input (768)
    const int sidx = (row_base + lr) * HHP + hcol_base + lc;   // buffer (776)
    const float ha = h0[gidx], hb = h0[gidx + 1];
    c_lds[lr][lc]     = c0[gidx];
    c_lds[lr][lc + 1] = c0[gidx + 1];
    const unsigned short ha_hi = f2bf(ha), hb_hi = f2bf(hb);
    __hip_atomic_store((unsigned*)hhi0 + (sidx >> 1),
                       (unsigned)ha_hi | ((unsigned)hb_hi << 16),
                       __ATOMIC_RELAXED, __HIP_MEMORY_SCOPE_AGENT);
    if (tid < 16) {
      const int row = row_base + tid;
      x_lds[tid] = xin[(row >> 1) * (SS * 2) + (row & 1)];   // t = 0
    }
  }
  __syncthreads();                           // s_fast + lds_ctr + LDS init
  const bool fast = (s_fast != 0);
  unsigned bars = 0;

  // ---- hoisted loop invariants (compiler can't hoist across barriers) ----
  const int lr_c = tid >> 5, lc_c = tid & 31;        // elementwise cell
  const int ch_c = lc_c >> 4, c4_c = (lc_c & 15) * 4;
  const f32x4 bq = *(const f32x4*)&bw_b[lc_c * 4];   // bias (4 gates of cell)
  const f32x4 wq = *(const f32x4*)&bw_w[lc_c * 4];   // x-weight (4 gates)
  float cc_reg = c_lds[lr_c][lc_c];                  // c state in register

  // ---- per-wave distributed barrier (R17; coherence ops = R6-proven) ----
  auto wbar = [&]() {
    asm volatile("s_waitcnt vmcnt(0)" ::: "memory");   // own stores -> L2
    ++bars;
    if (lane == 0) {
      const unsigned old = __hip_atomic_fetch_add(
          &lds_ctr, 1u, __ATOMIC_RELAXED, __HIP_MEMORY_SCOPE_WORKGROUP);
      if (old == 8u * bars - 1u)             // all 8 waves of block drained
        __hip_atomic_fetch_add(ctr, 1u, __ATOMIC_RELAXED,
                               __HIP_MEMORY_SCOPE_AGENT);
    }
    const unsigned want = (unsigned)GP * bars;
    while (__hip_atomic_load(ctr, __ATOMIC_RELAXED, __HIP_MEMORY_SCOPE_AGENT)
           < want) {}
  };

  wbar();                                    // h0/c0 published

  const unsigned short* hbhi[3] = {hhi0, hhi1, hhi2};
  unsigned short* wbhi[3] = {hhi0, hhi1, hhi2};

  const int frag_off = l15 * LDP + quad * 8; // A-frag LDS offset (shorts)
  const int wbase = wave * 64;               // wave-uniform lane base
  int cur = 0;

  for (int t = 0; t < SS; ++t) {
    const int nxt = (cur == 2) ? 0 : cur + 1;
    const unsigned short* rhi = hbhi[cur];
    unsigned short* whi = wbhi[nxt];

    // ---- stage group h-slice: identity copy 16 x 776 shorts (24832B) ----
    if (fast) {                              // async global->LDS, no VGPR trip
      const unsigned short* src = rhi + row_base * HHP;
#pragma unroll
      for (int i = 0; i < 3; ++i) {
        const int gi = i * 512 + tid;        // u128 idx (per-lane global src)
        gll16(src + gi * 8, &lds_hi[(i * 512 + wbase) * 8]);
      }
      if (tid < 16) {                        // tail u128s 1536..1551 (plain)
        const uint4v v = *(const uint4v*)(src + (1536 + tid) * 8);
        *(uint4v*)&lds_hi[(1536 + tid) * 8] = v;
      }
    } else {                                 // agent-scope (MALL) identity copy
      const unsigned long long* src64 =
          (const unsigned long long*)rhi + row_base * (HHP / 4);
#pragma unroll
      for (int i = 0; i < 6; ++i) {
        const int gi = i * 512 + tid;        // u64 idx in [0,3072)
        const unsigned long long vh = __hip_atomic_load(
            src64 + gi, __ATOMIC_RELAXED, __HIP_MEMORY_SCOPE_AGENT);
        *(unsigned long long*)&lds_hi[gi * 4] = vh;
      }
      if (tid < 32) {                        // tail u64s 3072..3103
        const int gi = 3072 + tid;
        const unsigned long long vh = __hip_atomic_load(
            src64 + gi, __ATOMIC_RELAXED, __HIP_MEMORY_SCOPE_AGENT);
        *(unsigned long long*)&lds_hi[gi * 4] = vh;
      }
    }
    __syncthreads();                         // drains vmcnt (gll) + lgkm

    // ---- GEMM: wave (colh,ks): 6kt x 4n, 1 MFMA/(ktl,n): h_hi*W_hi ----
    f32x4 acc[4] = {{0,0,0,0},{0,0,0,0},{0,0,0,0},{0,0,0,0}};
#pragma unroll
    for (int ktl = 0; ktl < 6; ++ktl) {
      const int kt = ks * 6 + ktl;
      const s16x8 ah = *(const s16x8*)&lds_hi[frag_off + kt * 32];
#pragma unroll
      for (int n = 0; n < 4; ++n)
        acc[n] = __builtin_amdgcn_mfma_f32_16x16x32_bf16(ah, Bhi[ktl][n], acc[n], 0, 0, 0);
    }

    // ---- partial write: C/D layout col=l15, row=quad*4+reg ----
#pragma unroll
    for (int n = 0; n < 4; ++n)
#pragma unroll
      for (int reg = 0; reg < 4; ++reg)
        part[colh][ks][quad * 4 + reg][n * 16 + l15] = acc[n][reg];
    __syncthreads();

    // ---- reduce over ks + bias + x*w0; elementwise; h store (1 cell/thr) --
    {
      const f32x4 s0 = *(const f32x4*)&part[ch_c][0][lr_c][c4_c];
      const f32x4 s1 = *(const f32x4*)&part[ch_c][1][lr_c][c4_c];
      const f32x4 s2 = *(const f32x4*)&part[ch_c][2][lr_c][c4_c];
      const f32x4 s3 = *(const f32x4*)&part[ch_c][3][lr_c][c4_c];
      const float xv = x_lds[lr_c];
      f32x4 gv = (s0 + s1) + (s2 + s3);
#pragma unroll
      for (int j = 0; j < 4; ++j) gv[j] += bq[j] + xv * wq[j];

      cc_reg = sigm(gv[1]) * cc_reg + sigm(gv[0]) * tanhf_(gv[2]);
      const float hh = gv[3] * tanhf_(cc_reg);  // no sigmoid on o-gate (ref)

      const unsigned short mhi = f2bf(hh);
      const unsigned ohi = (unsigned)__shfl_down((int)(unsigned)mhi, 1, 64);
      if ((tid & 1) == 0) {                  // lc_c even; neighbor = lc_c+1
        const int sidx = (row_base + lr_c) * HHP + hcol_base + lc_c;
        const unsigned ph = (unsigned)mhi | (ohi << 16);
        if (fast) {                          // write-through L1 -> XCD L2
          ((unsigned*)whi)[sidx >> 1] = ph;
        } else {
          __hip_atomic_store((unsigned*)whi + (sidx >> 1), ph, __ATOMIC_RELAXED, __HIP_MEMORY_SCOPE_AGENT);
        }
      }
      if (tid < 16 && t + 1 < SS) {
        const int row = row_base + tid;
        x_lds[tid] = xin[(row >> 1) * (SS * 2) + (t + 1) * 2 + (row & 1)];
      }
    }
    wbar();                                  // per-wave arrival + self-release
    cur = nxt;
  }

  // ---- output projection: final h in parity cur = 256%3 = 1 ----
  if (p == 0 && tid < 256) {
    const unsigned short* fhi = hbhi[cur];
    const int rloc = tid >> 4, s = tid & 15;
    const int row = row_base + rloc;
    float sum = 0.0f;
#pragma unroll
    for (int i = 0; i < 12; ++i) {
      const int u = row * (HHP / 4) + s * 12 + i;  // u64 idx; k0 = s*48 + i*4
      unsigned long long vh;
      if (fast) {                            // fresh in this XCD's L2
        vh = *((const unsigned long long*)fhi + u);
      } else {
        vh = __hip_atomic_load((unsigned long long*)fhi + u, __ATOMIC_RELAXED, __HIP_MEMORY_SCOPE_AGENT);
      }
#pragma unroll
      for (int j = 0; j < 4; ++j) {
        const float h = bf2f((unsigned short)(vh >> (16 * j)));
        sum += h * Wout[s * 48 + i * 4 + j];
      }
    }
#pragma unroll
    for (int off = 8; off; off >>= 1) sum += __shfl_down(sum, off, 16);
    if (s == 0) out[row] = sum + bout[0];
  }
}

extern "C" void kernel_launch(void* const* d_in, const int* in_sizes, int n_in,
                              void* d_out, int out_size, void* d_ws, size_t ws_size,
                              hipStream_t stream) {
  const float* xin  = (const float*)d_in[0];
  const float* h0   = (const float*)d_in[1];
  const float* c0   = (const float*)d_in[2];
  const float* Wi   = (const float*)d_in[3];
  const float* bi   = (const float*)d_in[4];
  const float* Wf   = (const float*)d_in[5];
  const float* bfv  = (const float*)d_in[6];
  const float* Wc   = (const float*)d_in[7];
  const float* bc   = (const float*)d_in[8];
  const float* Wo   = (const float*)d_in[9];
  const float* bo   = (const float*)d_in[10];
  const float* Wout = (const float*)d_in[11];
  const float* bout = (const float*)d_in[12];
  float* out = (float*)d_out;

  char* ws = (char*)d_ws;
  const size_t HB = (size_t)NROW * HHP * sizeof(unsigned short);  // 198656
  unsigned short* hhi0 = (unsigned short*)(ws);
  unsigned short* hhi1 = (unsigned short*)(ws + HB);
  unsigned short* hhi2 = (unsigned short*)(ws + 2 * HB);
  unsigned*       bar  = (unsigned*)(ws + 3 * HB);
  unsigned short* dummy = (unsigned short*)(ws + 3 * HB + 4096);  // unused lo

  hipMemsetAsync(bar, 0, 4096, stream);    // zero barrier/rendezvous counters

  (void)in_sizes; (void)n_in; (void)out_size; (void)ws_size;
  hipLaunchKernelGGL(lstm_persistent, dim3(GR * GP), dim3(512), 0, stream,
                     xin, h0, c0, Wi, bi, Wf, bfv, Wc, bc, Wo, bo,
                     Wout, bout, out, hhi0, hhi1, hhi2, dummy, dummy, dummy, bar);
}

// Round 11
// 855.190 us; speedup vs baseline: 1.4966x; 1.4966x over previous
//
#include <hip/hip_runtime.h>

typedef float f32x4 __attribute__((ext_vector_type(4)));
typedef short s16x8 __attribute__((ext_vector_type(8)));
typedef unsigned uint4v __attribute__((ext_vector_type(4)));

#define HH   768
#define HHP  776   // h-buffer row pitch in shorts (GLOBAL and LDS identical)
#define SS   256
#define GR   8     // row groups (16 rows each); g = blockIdx & 7
#define GP   24    // col blocks per group; p = blockIdx >> 3
#define NROW 128
#define LDP  776   // LDS row pitch (shorts); 1552B = 16B-aligned rows
#define PP   68    // partials row pitch (floats)

__device__ __forceinline__ unsigned short f2bf(float f) {
  unsigned int u = __float_as_uint(f);
  u += 0x7FFFu + ((u >> 16) & 1u);          // RTNE
  return (unsigned short)(u >> 16);
}
__device__ __forceinline__ float bf2f(unsigned short s) {
  return __uint_as_float(((unsigned int)s) << 16);
}
__device__ __forceinline__ float sigm(float v) { return 1.0f / (1.0f + __expf(-v)); }
__device__ __forceinline__ float tanhf_(float v) {
  return 1.0f - 2.0f / (__expf(2.0f * v) + 1.0f);
}
// async global->LDS, 16B per lane; dest = wave-uniform base + lane*16 (HW).
__device__ __forceinline__ void gll16(const void* gp, void* lp) {
  __builtin_amdgcn_global_load_lds(
      (const __attribute__((address_space(1))) unsigned*)gp,
      (__attribute__((address_space(3))) unsigned*)lp, 16, 0, 0);
}

// 192 blocks x 512 threads (8 waves, 2/SIMD via launch_bounds(512,2)).
// Static roles: g = blockIdx&7 (rows [16g,16g+16)), p = blockIdx>>3 (hidden
// cols [32p,32p+32)); gate cols permuted col = hcol*4 + gate.
// Wave w: colh = w&1 (64-gate-col half), ks = w>>1 (6-kt slice of K).
// R12 (WIN 968->830): h transported bf16-only. R14 (neutral, kept): staging
// via global_load_lds w=16, pitch-776 identity copy. R15 (WIN 830->687,
// steady 624): W single-bf16 — 24 MFMA/wave. R16 (neutral, kept): bias/
// x-weight + c-state hoisted to registers; sleepless tid0 poll.
// R18 (this round): SHARDED arrival counters. Same R6-proven structure
// (per-wave vmcnt drain -> __syncthreads -> tid0 arrival RMW -> tid0 poll
// -> __syncthreads release) and same coherence ops; the ONLY change: the
// 24 arrival RMWs are spread over 4 counters on 4 distinct 256B-spaced
// lines (6 blocks each), removing the same-line RMW serialization tail
// (R13 evidence: same-line atomic traffic costs ~10-30cy/op serial). tid0
// polls all 4 shards per iteration (4 back-to-back independent loads = one
// RT per 4 samples; 24 pollers only — 50x below R17's flood).
// Closed dead ends (do not revisit): R8 flag-poll, R9 sc0-load poll (hang),
// R13 local RMW-poll (+230cy/step), R17 all-wave poll flood (2x regression),
// R10 direct-L2 A-frags (-32%), R11 split-phase staging (-18%),
// wave-per-n-tile & 1024-thread restructures (rejected on paper: LDS-port /
// per-CU work double).
__global__ void __launch_bounds__(512, 2) lstm_persistent(
    const float* __restrict__ xin, const float* __restrict__ h0,
    const float* __restrict__ c0,
    const float* __restrict__ Wi, const float* __restrict__ bi,
    const float* __restrict__ Wf, const float* __restrict__ bfv,
    const float* __restrict__ Wc, const float* __restrict__ bc,
    const float* __restrict__ Wo, const float* __restrict__ bo,
    const float* __restrict__ Wout, const float* __restrict__ bout,
    float* __restrict__ out,
    unsigned short* __restrict__ hhi0, unsigned short* __restrict__ hhi1,
    unsigned short* __restrict__ hhi2,
    unsigned short* __restrict__ hlo0, unsigned short* __restrict__ hlo1,
    unsigned short* __restrict__ hlo2,
    unsigned* __restrict__ bar)
{
  const int tid = threadIdx.x, wave = tid >> 6, lane = tid & 63;
  const int l15 = lane & 15, quad = lane >> 4;
  const int g = blockIdx.x & 7, p = blockIdx.x >> 3;
  const int row_base = g * 16, hcol_base = p * 32;
  const int colh = wave & 1, ks = wave >> 1;   // col-half / kt-slice

  __shared__ __align__(16) unsigned short lds_hi[16 * LDP];
  __shared__ __align__(16) float part[2][4][16][PP];   // [colh][ks][row][col64]
  __shared__ float bw_b[128], bw_w[128];               // bias / x-weight per col
  __shared__ float c_lds[16][33];                      // init handoff only
  __shared__ float x_lds[16];
  __shared__ int s_fast;

  unsigned* shv = bar + g * 256;             // 4 shards: words s*64 (256B apart)
  unsigned* myshard = shv + (p / 6) * 64;    // 6 blocks per shard
  unsigned* rdy = bar + 2048 + g * 16;       // rendezvous counter
  unsigned* ids = bar + 2176 + g * 32;       // 24 published XCC_IDs

  // ---- one-time vote (tid0): all 24 members on one XCD? [R6-proven] ----
  if (tid == 0) {
    const unsigned my = (__builtin_amdgcn_s_getreg(20 | (3 << 11)) & 15u) + 1u;
    __hip_atomic_store(ids + p, my, __ATOMIC_RELAXED, __HIP_MEMORY_SCOPE_AGENT);
    __hip_atomic_fetch_add(rdy, 1u, __ATOMIC_RELEASE, __HIP_MEMORY_SCOPE_AGENT);
    while (__hip_atomic_load(rdy, __ATOMIC_ACQUIRE, __HIP_MEMORY_SCOPE_AGENT)
           < (unsigned)GP)
      __builtin_amdgcn_s_sleep(8);
    int ok = 1;
    for (int q = 0; q < GP; ++q)
      ok &= (__hip_atomic_load(ids + q, __ATOMIC_RELAXED,
                               __HIP_MEMORY_SCOPE_AGENT) == my);
    s_fast = ok;
  }

  // ---- one-time: weights -> bf16 hi B-fragments (n=lane&15, k=quad*8+j) --
  s16x8 Bhi[6][4];
#pragma unroll
  for (int n = 0; n < 4; ++n) {
    const int col = p * 128 + colh * 64 + n * 16 + l15;  // permuted gate col
    const int gg = col & 3, hc = col >> 2;
    const float* W = (gg == 0) ? Wi : (gg == 1) ? Wf : (gg == 2) ? Wc : Wo;
#pragma unroll
    for (int ktl = 0; ktl < 6; ++ktl) {
      const int kt = ks * 6 + ktl;
      s16x8 vh;
#pragma unroll
      for (int j = 0; j < 8; ++j) {
        const int k = kt * 32 + quad * 8 + j;
        vh[j] = (short)f2bf(W[(1 + k) * HH + hc]);
      }
      Bhi[ktl][n] = vh;
    }
  }

  // ---- one-time: bias + x-weight tables -> LDS (per permuted gate col) ----
  if (tid < 128) {
    const int gg = tid & 3;
    const int hc = p * 32 + (tid >> 2);
    const float* W  = (gg == 0) ? Wi : (gg == 1) ? Wf : (gg == 2) ? Wc : Wo;
    const float* bb = (gg == 0) ? bi : (gg == 1) ? bfv : (gg == 2) ? bc : bo;
    bw_b[tid] = bb[hc];
    bw_w[tid] = W[hc];                       // W row 0 = x weight (exact fp32)
  }

  // ---- init: c->LDS; h0 -> parity-0 hi buffer (agent stores, pitch 776) --
  if (tid < 256) {
    const int lr = tid >> 4, lc = (tid & 15) * 2;
    const int gidx = (row_base + lr) * HH + hcol_base + lc;    // input (768)
    const int sidx = (row_base + lr) * HHP + hcol_base + lc;   // buffer (776)
    const float ha = h0[gidx], hb = h0[gidx + 1];
    c_lds[lr][lc]     = c0[gidx];
    c_lds[lr][lc + 1] = c0[gidx + 1];
    const unsigned short ha_hi = f2bf(ha), hb_hi = f2bf(hb);
    __hip_atomic_store((unsigned*)hhi0 + (sidx >> 1),
                       (unsigned)ha_hi | ((unsigned)hb_hi << 16),
                       __ATOMIC_RELAXED, __HIP_MEMORY_SCOPE_AGENT);
    if (tid < 16) {
      const int row = row_base + tid;
      x_lds[tid] = xin[(row >> 1) * (SS * 2) + (row & 1)];   // t = 0
    }
  }
  __syncthreads();                           // s_fast + LDS init visible
  const bool fast = (s_fast != 0);
  unsigned bars = 0;

  // Agent-scope counter barrier, R6 structure; R18: arrivals sharded 4-way
  // (myshard), tid0 polls all 4 shards per iteration (pipelined loads).
  auto gbar = [&]() {
    __builtin_amdgcn_s_waitcnt(0);
    __syncthreads();
    if (tid == 0) {
      ++bars;
      __hip_atomic_fetch_add(myshard, 1u, __ATOMIC_RELAXED,
                             __HIP_MEMORY_SCOPE_AGENT);
      const unsigned want = 6u * bars;       // 6 arrivals per shard per step
      for (;;) {
        const unsigned a0 = __hip_atomic_load(shv,       __ATOMIC_RELAXED, __HIP_MEMORY_SCOPE_AGENT);
        const unsigned a1 = __hip_atomic_load(shv + 64,  __ATOMIC_RELAXED, __HIP_MEMORY_SCOPE_AGENT);
        const unsigned a2 = __hip_atomic_load(shv + 128, __ATOMIC_RELAXED, __HIP_MEMORY_SCOPE_AGENT);
        const unsigned a3 = __hip_atomic_load(shv + 192, __ATOMIC_RELAXED, __HIP_MEMORY_SCOPE_AGENT);
        if (a0 >= want && a1 >= want && a2 >= want && a3 >= want) break;
      }
    }
    __syncthreads();
  };

  // ---- hoisted loop invariants (compiler can't hoist across barriers) ----
  const int lr_c = tid >> 5, lc_c = tid & 31;        // elementwise cell
  const int ch_c = lc_c >> 4, c4_c = (lc_c & 15) * 4;
  const f32x4 bq = *(const f32x4*)&bw_b[lc_c * 4];   // bias (4 gates of cell)
  const f32x4 wq = *(const f32x4*)&bw_w[lc_c * 4];   // x-weight (4 gates)
  float cc_reg = c_lds[lr_c][lc_c];                  // c state in register

  gbar();                                    // h0/c0 published

  const unsigned short* hbhi[3] = {hhi0, hhi1, hhi2};
  unsigned short* wbhi[3] = {hhi0, hhi1, hhi2};

  const int frag_off = l15 * LDP + quad * 8; // A-frag LDS offset (shorts)
  const int wbase = wave * 64;               // wave-uniform lane base
  int cur = 0;

  for (int t = 0; t < SS; ++t) {
    const int nxt = (cur == 2) ? 0 : cur + 1;
    const unsigned short* rhi = hbhi[cur];
    unsigned short* whi = wbhi[nxt];

    // ---- stage group h-slice: identity copy 16 x 776 shorts (24832B) ----
    if (fast) {                              // async global->LDS, no VGPR trip
      const unsigned short* src = rhi + row_base * HHP;
#pragma unroll
      for (int i = 0; i < 3; ++i) {
        const int gi = i * 512 + tid;        // u128 idx (per-lane global src)
        gll16(src + gi * 8, &lds_hi[(i * 512 + wbase) * 8]);
      }
      if (tid < 16) {                        // tail u128s 1536..1551 (plain)
        const uint4v v = *(const uint4v*)(src + (1536 + tid) * 8);
        *(uint4v*)&lds_hi[(1536 + tid) * 8] = v;
      }
    } else {                                 // agent-scope (MALL) identity copy
      const unsigned long long* src64 =
          (const unsigned long long*)rhi + row_base * (HHP / 4);
#pragma unroll
      for (int i = 0; i < 6; ++i) {
        const int gi = i * 512 + tid;        // u64 idx in [0,3072)
        const unsigned long long vh = __hip_atomic_load(
            src64 + gi, __ATOMIC_RELAXED, __HIP_MEMORY_SCOPE_AGENT);
        *(unsigned long long*)&lds_hi[gi * 4] = vh;
      }
      if (tid < 32) {                        // tail u64s 3072..3103
        const int gi = 3072 + tid;
        const unsigned long long vh = __hip_atomic_load(
            src64 + gi, __ATOMIC_RELAXED, __HIP_MEMORY_SCOPE_AGENT);
        *(unsigned long long*)&lds_hi[gi * 4] = vh;
      }
    }
    __syncthreads();                         // drains vmcnt (gll) + lgkm

    // ---- GEMM: wave (colh,ks): 6kt x 4n, 1 MFMA/(ktl,n): h_hi*W_hi ----
    f32x4 acc[4] = {{0,0,0,0},{0,0,0,0},{0,0,0,0},{0,0,0,0}};
#pragma unroll
    for (int ktl = 0; ktl < 6; ++ktl) {
      const int kt = ks * 6 + ktl;
      const s16x8 ah = *(const s16x8*)&lds_hi[frag_off + kt * 32];
#pragma unroll
      for (int n = 0; n < 4; ++n)
        acc[n] = __builtin_amdgcn_mfma_f32_16x16x32_bf16(ah, Bhi[ktl][n], acc[n], 0, 0, 0);
    }

    // ---- partial write: C/D layout col=l15, row=quad*4+reg ----
#pragma unroll
    for (int n = 0; n < 4; ++n)
#pragma unroll
      for (int reg = 0; reg < 4; ++reg)
        part[colh][ks][quad * 4 + reg][n * 16 + l15] = acc[n][reg];
    __syncthreads();

    // ---- reduce over ks + bias + x*w0; elementwise; h store (1 cell/thr) --
    {
      const f32x4 s0 = *(const f32x4*)&part[ch_c][0][lr_c][c4_c];
      const f32x4 s1 = *(const f32x4*)&part[ch_c][1][lr_c][c4_c];
      const f32x4 s2 = *(const f32x4*)&part[ch_c][2][lr_c][c4_c];
      const f32x4 s3 = *(const f32x4*)&part[ch_c][3][lr_c][c4_c];
      const float xv = x_lds[lr_c];
      f32x4 gv = (s0 + s1) + (s2 + s3);
#pragma unroll
      for (int j = 0; j < 4; ++j) gv[j] += bq[j] + xv * wq[j];

      cc_reg = sigm(gv[1]) * cc_reg + sigm(gv[0]) * tanhf_(gv[2]);
      const float hh = gv[3] * tanhf_(cc_reg);  // no sigmoid on o-gate (ref)

      const unsigned short mhi = f2bf(hh);
      const unsigned ohi = (unsigned)__shfl_down((int)(unsigned)mhi, 1, 64);
      if ((tid & 1) == 0) {                  // lc_c even; neighbor = lc_c+1
        const int sidx = (row_base + lr_c) * HHP + hcol_base + lc_c;
        const unsigned ph = (unsigned)mhi | (ohi << 16);
        if (fast) {                          // write-through L1 -> XCD L2
          ((unsigned*)whi)[sidx >> 1] = ph;
        } else {
          __hip_atomic_store((unsigned*)whi + (sidx >> 1), ph, __ATOMIC_RELAXED, __HIP_MEMORY_SCOPE_AGENT);
        }
      }
      if (tid < 16 && t + 1 < SS) {
        const int row = row_base + tid;
        x_lds[tid] = xin[(row >> 1) * (SS * 2) + (t + 1) * 2 + (row & 1)];
      }
    }
    gbar();
    cur = nxt;
  }

  // ---- output projection: final h in parity cur = 256%3 = 1 ----
  if (p == 0 && tid < 256) {
    const unsigned short* fhi = hbhi[cur];
    const int rloc = tid >> 4, s = tid & 15;
    const int row = row_base + rloc;
    float sum = 0.0f;
#pragma unroll
    for (int i = 0; i < 12; ++i) {
      const int u = row * (HHP / 4) + s * 12 + i;  // u64 idx; k0 = s*48 + i*4
      unsigned long long vh;
      if (fast) {                            // fresh in this XCD's L2
        vh = *((const unsigned long long*)fhi + u);
      } else {
        vh = __hip_atomic_load((unsigned long long*)fhi + u, __ATOMIC_RELAXED, __HIP_MEMORY_SCOPE_AGENT);
      }
#pragma unroll
      for (int j = 0; j < 4; ++j) {
        const float h = bf2f((unsigned short)(vh >> (16 * j)));
        sum += h * Wout[s * 48 + i * 4 + j];
      }
    }
#pragma unroll
    for (int off = 8; off; off >>= 1) sum += __shfl_down(sum, off, 16);
    if (s == 0) out[row] = sum + bout[0];
  }
}

extern "C" void kernel_launch(void* const* d_in, const int* in_sizes, int n_in,
                              void* d_out, int out_size, void* d_ws, size_t ws_size,
                              hipStream_t stream) {
  const float* xin  = (const float*)d_in[0];
  const float* h0   = (const float*)d_in[1];
  const float* c0   = (const float*)d_in[2];
  const float* Wi   = (const float*)d_in[3];
  const float* bi   = (const float*)d_in[4];
  const float* Wf   = (const float*)d_in[5];
  const float* bfv  = (const float*)d_in[6];
  const float* Wc   = (const float*)d_in[7];
  const float* bc   = (const float*)d_in[8];
  const float* Wo   = (const float*)d_in[9];
  const float* bo   = (const float*)d_in[10];
  const float* Wout = (const float*)d_in[11];
  const float* bout = (const float*)d_in[12];
  float* out = (float*)d_out;

  char* ws = (char*)d_ws;
  const size_t HB = (size_t)NROW * HHP * sizeof(unsigned short);  // 198656
  unsigned short* hhi0 = (unsigned short*)(ws);
  unsigned short* hhi1 = (unsigned short*)(ws + HB);
  unsigned short* hhi2 = (unsigned short*)(ws + 2 * HB);
  unsigned*       bar  = (unsigned*)(ws + 3 * HB);
  unsigned short* dummy = (unsigned short*)(ws + 3 * HB + 16384);  // unused lo

  hipMemsetAsync(bar, 0, 12288, stream);   // zero shards + rendezvous + ids

  (void)in_sizes; (void)n_in; (void)out_size; (void)ws_size;
  hipLaunchKernelGGL(lstm_persistent, dim3(GR * GP), dim3(512), 0, stream,
                     xin, h0, c0, Wi, bi, Wf, bfv, Wc, bc, Wo, bo,
                     Wout, bout, out, hhi0, hhi1, hhi2, dummy, dummy, dummy, bar);
}

// Round 12
// 702.413 us; speedup vs baseline: 1.8222x; 1.2175x over previous
//
#include <hip/hip_runtime.h>

typedef float f32x4 __attribute__((ext_vector_type(4)));
typedef short s16x8 __attribute__((ext_vector_type(8)));
typedef unsigned uint4v __attribute__((ext_vector_type(4)));

#define HH   768
#define HHP  776   // h-buffer row pitch in shorts (GLOBAL and LDS identical)
#define SS   256
#define GR   8     // row groups (16 rows each); g = blockIdx & 7
#define GP   24    // col blocks per group; p = blockIdx >> 3
#define NROW 128
#define LDP  776   // LDS row pitch (shorts); 1552B = 16B-aligned rows
#define PP   68    // partials row pitch (floats)

__device__ __forceinline__ unsigned short f2bf(float f) {
  unsigned int u = __float_as_uint(f);
  u += 0x7FFFu + ((u >> 16) & 1u);          // RTNE
  return (unsigned short)(u >> 16);
}
__device__ __forceinline__ float bf2f(unsigned short s) {
  return __uint_as_float(((unsigned int)s) << 16);
}
__device__ __forceinline__ float sigm(float v) { return 1.0f / (1.0f + __expf(-v)); }
__device__ __forceinline__ float tanhf_(float v) {
  return 1.0f - 2.0f / (__expf(2.0f * v) + 1.0f);
}
// async global->LDS, 16B per lane; dest = wave-uniform base + lane*16 (HW).
__device__ __forceinline__ void gll16(const void* gp, void* lp) {
  __builtin_amdgcn_global_load_lds(
      (const __attribute__((address_space(1))) unsigned*)gp,
      (__attribute__((address_space(3))) unsigned*)lp, 16, 0, 0);
}

// 192 blocks x 512 threads (8 waves, 2/SIMD via launch_bounds(512,2)).
// Static roles: g = blockIdx&7 (rows [16g,16g+16)), p = blockIdx>>3 (hidden
// cols [32p,32p+32)); gate cols permuted col = hcol*4 + gate.
// Wave w: colh = w&1 (64-gate-col half), ks = w>>1 (6-kt slice of K).
// R12 (WIN 968->830): h transported bf16-only. R14 (neutral, kept): staging
// via global_load_lds w=16, pitch-776 identity copy. R15 (WIN 830->687,
// steady 624): W single-bf16 — 24 MFMA/wave. R16 (neutral, kept): bias/
// x-weight + c-state in registers; sleepless tid0 poll.
// R19 (this round): LDS-relay ARRIVAL (pre-sync removed). Each wave drains
// its OWN stores (s_waitcnt vmcnt(0), per-wave) then lane0 bumps a monotonic
// LDS counter; tid0 ALONE spins on the LDS counter (==8*bars) — validated
// arrival half of R17 — then performs the R6-proven agent arrival RMW +
// agent poll (1 RMW + 1 poller per block, unchanged), then the release
// __syncthreads. Removes one full barrier crossing per step and fires the
// arrival as soon as the last wave drains. Global coherence ops byte-
// identical to R6.
// Closed dead ends (do not revisit): R8 flag-poll, R9 sc0-load poll (hang),
// R13 local RMW-poll, R17 all-wave global poll flood (2x), R18 sharded
// counters (+25%), R10 direct-L2 A-frags (-32%), R11 split-phase staging
// (-18%), wave-per-n-tile / 2-way-ks / pitch-808 (rejected on paper: LDS
// port math).
__global__ void __launch_bounds__(512, 2) lstm_persistent(
    const float* __restrict__ xin, const float* __restrict__ h0,
    const float* __restrict__ c0,
    const float* __restrict__ Wi, const float* __restrict__ bi,
    const float* __restrict__ Wf, const float* __restrict__ bfv,
    const float* __restrict__ Wc, const float* __restrict__ bc,
    const float* __restrict__ Wo, const float* __restrict__ bo,
    const float* __restrict__ Wout, const float* __restrict__ bout,
    float* __restrict__ out,
    unsigned short* __restrict__ hhi0, unsigned short* __restrict__ hhi1,
    unsigned short* __restrict__ hhi2,
    unsigned short* __restrict__ hlo0, unsigned short* __restrict__ hlo1,
    unsigned short* __restrict__ hlo2,
    unsigned* __restrict__ bar)
{
  const int tid = threadIdx.x, wave = tid >> 6, lane = tid & 63;
  const int l15 = lane & 15, quad = lane >> 4;
  const int g = blockIdx.x & 7, p = blockIdx.x >> 3;
  const int row_base = g * 16, hcol_base = p * 32;
  const int colh = wave & 1, ks = wave >> 1;   // col-half / kt-slice

  __shared__ __align__(16) unsigned short lds_hi[16 * LDP];
  __shared__ __align__(16) float part[2][4][16][PP];   // [colh][ks][row][col64]
  __shared__ float bw_b[128], bw_w[128];               // bias / x-weight per col
  __shared__ float c_lds[16][33];                      // init handoff only
  __shared__ float x_lds[16];
  __shared__ unsigned lds_ctr;                         // monotonic wave arrivals
  __shared__ int s_fast;

  unsigned* ctr = bar + g * 64;              // step barrier (256B-spaced)
  unsigned* rdy = bar + 512 + g * 16;        // rendezvous counter
  unsigned* ids = bar + 640 + g * 32;        // 24 published XCC_IDs

  // ---- one-time vote (tid0): all 24 members on one XCD? [R6-proven] ----
  if (tid == 0) {
    lds_ctr = 0;
    const unsigned my = (__builtin_amdgcn_s_getreg(20 | (3 << 11)) & 15u) + 1u;
    __hip_atomic_store(ids + p, my, __ATOMIC_RELAXED, __HIP_MEMORY_SCOPE_AGENT);
    __hip_atomic_fetch_add(rdy, 1u, __ATOMIC_RELEASE, __HIP_MEMORY_SCOPE_AGENT);
    while (__hip_atomic_load(rdy, __ATOMIC_ACQUIRE, __HIP_MEMORY_SCOPE_AGENT)
           < (unsigned)GP)
      __builtin_amdgcn_s_sleep(8);
    int ok = 1;
    for (int q = 0; q < GP; ++q)
      ok &= (__hip_atomic_load(ids + q, __ATOMIC_RELAXED,
                               __HIP_MEMORY_SCOPE_AGENT) == my);
    s_fast = ok;
  }

  // ---- one-time: weights -> bf16 hi B-fragments (n=lane&15, k=quad*8+j) --
  s16x8 Bhi[6][4];
#pragma unroll
  for (int n = 0; n < 4; ++n) {
    const int col = p * 128 + colh * 64 + n * 16 + l15;  // permuted gate col
    const int gg = col & 3, hc = col >> 2;
    const float* W = (gg == 0) ? Wi : (gg == 1) ? Wf : (gg == 2) ? Wc : Wo;
#pragma unroll
    for (int ktl = 0; ktl < 6; ++ktl) {
      const int kt = ks * 6 + ktl;
      s16x8 vh;
#pragma unroll
      for (int j = 0; j < 8; ++j) {
        const int k = kt * 32 + quad * 8 + j;
        vh[j] = (short)f2bf(W[(1 + k) * HH + hc]);
      }
      Bhi[ktl][n] = vh;
    }
  }

  // ---- one-time: bias + x-weight tables -> LDS (per permuted gate col) ----
  if (tid < 128) {
    const int gg = tid & 3;
    const int hc = p * 32 + (tid >> 2);
    const float* W  = (gg == 0) ? Wi : (gg == 1) ? Wf : (gg == 2) ? Wc : Wo;
    const float* bb = (gg == 0) ? bi : (gg == 1) ? bfv : (gg == 2) ? bc : bo;
    bw_b[tid] = bb[hc];
    bw_w[tid] = W[hc];                       // W row 0 = x weight (exact fp32)
  }

  // ---- init: c->LDS; h0 -> parity-0 hi buffer (agent stores, pitch 776) --
  if (tid < 256) {
    const int lr = tid >> 4, lc = (tid & 15) * 2;
    const int gidx = (row_base + lr) * HH + hcol_base + lc;    // input (768)
    const int sidx = (row_base + lr) * HHP + hcol_base + lc;   // buffer (776)
    const float ha = h0[gidx], hb = h0[gidx + 1];
    c_lds[lr][lc]     = c0[gidx];
    c_lds[lr][lc + 1] = c0[gidx + 1];
    const unsigned short ha_hi = f2bf(ha), hb_hi = f2bf(hb);
    __hip_atomic_store((unsigned*)hhi0 + (sidx >> 1),
                       (unsigned)ha_hi | ((unsigned)hb_hi << 16),
                       __ATOMIC_RELAXED, __HIP_MEMORY_SCOPE_AGENT);
    if (tid < 16) {
      const int row = row_base + tid;
      x_lds[tid] = xin[(row >> 1) * (SS * 2) + (row & 1)];   // t = 0
    }
  }
  __syncthreads();                           // s_fast + lds_ctr + LDS init
  const bool fast = (s_fast != 0);
  unsigned bars = 0;

  // R19 step barrier: per-wave drain -> LDS arrival -> tid0 LDS-spin ->
  // R6-proven agent arrival + poll -> release sync.
  auto gbar = [&]() {
    asm volatile("s_waitcnt vmcnt(0)" ::: "memory");  // own h stores -> L2
    ++bars;
    if (lane == 0)
      __hip_atomic_fetch_add(&lds_ctr, 1u, __ATOMIC_RELEASE,
                             __HIP_MEMORY_SCOPE_WORKGROUP);
    if (tid == 0) {
      while (__hip_atomic_load(&lds_ctr, __ATOMIC_ACQUIRE,
                               __HIP_MEMORY_SCOPE_WORKGROUP) < 8u * bars) {}
      __hip_atomic_fetch_add(ctr, 1u, __ATOMIC_RELAXED, __HIP_MEMORY_SCOPE_AGENT);
      const unsigned want = (unsigned)GP * bars;
      while (__hip_atomic_load(ctr, __ATOMIC_RELAXED, __HIP_MEMORY_SCOPE_AGENT) < want) {}
    }
    __syncthreads();                         // release (R6 relay shape)
  };

  // ---- hoisted loop invariants (compiler can't hoist across barriers) ----
  const int lr_c = tid >> 5, lc_c = tid & 31;        // elementwise cell
  const int ch_c = lc_c >> 4, c4_c = (lc_c & 15) * 4;
  const f32x4 bq = *(const f32x4*)&bw_b[lc_c * 4];   // bias (4 gates of cell)
  const f32x4 wq = *(const f32x4*)&bw_w[lc_c * 4];   // x-weight (4 gates)
  float cc_reg = c_lds[lr_c][lc_c];                  // c state in register

  gbar();                                    // h0/c0 published

  const unsigned short* hbhi[3] = {hhi0, hhi1, hhi2};
  unsigned short* wbhi[3] = {hhi0, hhi1, hhi2};

  const int frag_off = l15 * LDP + quad * 8; // A-frag LDS offset (shorts)
  const int wbase = wave * 64;               // wave-uniform lane base
  int cur = 0;

  for (int t = 0; t < SS; ++t) {
    const int nxt = (cur == 2) ? 0 : cur + 1;
    const unsigned short* rhi = hbhi[cur];
    unsigned short* whi = wbhi[nxt];

    // ---- stage group h-slice: identity copy 16 x 776 shorts (24832B) ----
    if (fast) {                              // async global->LDS, no VGPR trip
      const unsigned short* src = rhi + row_base * HHP;
#pragma unroll
      for (int i = 0; i < 3; ++i) {
        const int gi = i * 512 + tid;        // u128 idx (per-lane global src)
        gll16(src + gi * 8, &lds_hi[(i * 512 + wbase) * 8]);
      }
      if (tid < 16) {                        // tail u128s 1536..1551 (plain)
        const uint4v v = *(const uint4v*)(src + (1536 + tid) * 8);
        *(uint4v*)&lds_hi[(1536 + tid) * 8] = v;
      }
    } else {                                 // agent-scope (MALL) identity copy
      const unsigned long long* src64 =
          (const unsigned long long*)rhi + row_base * (HHP / 4);
#pragma unroll
      for (int i = 0; i < 6; ++i) {
        const int gi = i * 512 + tid;        // u64 idx in [0,3072)
        const unsigned long long vh = __hip_atomic_load(
            src64 + gi, __ATOMIC_RELAXED, __HIP_MEMORY_SCOPE_AGENT);
        *(unsigned long long*)&lds_hi[gi * 4] = vh;
      }
      if (tid < 32) {                        // tail u64s 3072..3103
        const int gi = 3072 + tid;
        const unsigned long long vh = __hip_atomic_load(
            src64 + gi, __ATOMIC_RELAXED, __HIP_MEMORY_SCOPE_AGENT);
        *(unsigned long long*)&lds_hi[gi * 4] = vh;
      }
    }
    __syncthreads();                         // drains vmcnt (gll) + lgkm

    // ---- GEMM: wave (colh,ks): 6kt x 4n, 1 MFMA/(ktl,n): h_hi*W_hi ----
    f32x4 acc[4] = {{0,0,0,0},{0,0,0,0},{0,0,0,0},{0,0,0,0}};
#pragma unroll
    for (int ktl = 0; ktl < 6; ++ktl) {
      const int kt = ks * 6 + ktl;
      const s16x8 ah = *(const s16x8*)&lds_hi[frag_off + kt * 32];
#pragma unroll
      for (int n = 0; n < 4; ++n)
        acc[n] = __builtin_amdgcn_mfma_f32_16x16x32_bf16(ah, Bhi[ktl][n], acc[n], 0, 0, 0);
    }

    // ---- partial write: C/D layout col=l15, row=quad*4+reg ----
#pragma unroll
    for (int n = 0; n < 4; ++n)
#pragma unroll
      for (int reg = 0; reg < 4; ++reg)
        part[colh][ks][quad * 4 + reg][n * 16 + l15] = acc[n][reg];
    __syncthreads();

    // ---- reduce over ks + bias + x*w0; elementwise; h store (1 cell/thr) --
    {
      const f32x4 s0 = *(const f32x4*)&part[ch_c][0][lr_c][c4_c];
      const f32x4 s1 = *(const f32x4*)&part[ch_c][1][lr_c][c4_c];
      const f32x4 s2 = *(const f32x4*)&part[ch_c][2][lr_c][c4_c];
      const f32x4 s3 = *(const f32x4*)&part[ch_c][3][lr_c][c4_c];
      const float xv = x_lds[lr_c];
      f32x4 gv = (s0 + s1) + (s2 + s3);
#pragma unroll
      for (int j = 0; j < 4; ++j) gv[j] += bq[j] + xv * wq[j];

      cc_reg = sigm(gv[1]) * cc_reg + sigm(gv[0]) * tanhf_(gv[2]);
      const float hh = gv[3] * tanhf_(cc_reg);  // no sigmoid on o-gate (ref)

      const unsigned short mhi = f2bf(hh);
      const unsigned ohi = (unsigned)__shfl_down((int)(unsigned)mhi, 1, 64);
      if ((tid & 1) == 0) {                  // lc_c even; neighbor = lc_c+1
        const int sidx = (row_base + lr_c) * HHP + hcol_base + lc_c;
        const unsigned ph = (unsigned)mhi | (ohi << 16);
        if (fast) {                          // write-through L1 -> XCD L2
          ((unsigned*)whi)[sidx >> 1] = ph;
        } else {
          __hip_atomic_store((unsigned*)whi + (sidx >> 1), ph, __ATOMIC_RELAXED, __HIP_MEMORY_SCOPE_AGENT);
        }
      }
      if (tid < 16 && t + 1 < SS) {
        const int row = row_base + tid;
        x_lds[tid] = xin[(row >> 1) * (SS * 2) + (t + 1) * 2 + (row & 1)];
      }
    }
    gbar();
    cur = nxt;
  }

  // ---- output projection: final h in parity cur = 256%3 = 1 ----
  if (p == 0 && tid < 256) {
    const unsigned short* fhi = hbhi[cur];
    const int rloc = tid >> 4, s = tid & 15;
    const int row = row_base + rloc;
    float sum = 0.0f;
#pragma unroll
    for (int i = 0; i < 12; ++i) {
      const int u = row * (HHP / 4) + s * 12 + i;  // u64 idx; k0 = s*48 + i*4
      unsigned long long vh;
      if (fast) {                            // fresh in this XCD's L2
        vh = *((const unsigned long long*)fhi + u);
      } else {
        vh = __hip_atomic_load((unsigned long long*)fhi + u, __ATOMIC_RELAXED, __HIP_MEMORY_SCOPE_AGENT);
      }
#pragma unroll
      for (int j = 0; j < 4; ++j) {
        const float h = bf2f((unsigned short)(vh >> (16 * j)));
        sum += h * Wout[s * 48 + i * 4 + j];
      }
    }
#pragma unroll
    for (int off = 8; off; off >>= 1) sum += __shfl_down(sum, off, 16);
    if (s == 0) out[row] = sum + bout[0];
  }
}

extern "C" void kernel_launch(void* const* d_in, const int* in_sizes, int n_in,
                              void* d_out, int out_size, void* d_ws, size_t ws_size,
                              hipStream_t stream) {
  const float* xin  = (const float*)d_in[0];
  const float* h0   = (const float*)d_in[1];
  const float* c0   = (const float*)d_in[2];
  const float* Wi   = (const float*)d_in[3];
  const float* bi   = (const float*)d_in[4];
  const float* Wf   = (const float*)d_in[5];
  const float* bfv  = (const float*)d_in[6];
  const float* Wc   = (const float*)d_in[7];
  const float* bc   = (const float*)d_in[8];
  const float* Wo   = (const float*)d_in[9];
  const float* bo   = (const float*)d_in[10];
  const float* Wout = (const float*)d_in[11];
  const float* bout = (const float*)d_in[12];
  float* out = (float*)d_out;

  char* ws = (char*)d_ws;
  const size_t HB = (size_t)NROW * HHP * sizeof(unsigned short);  // 198656
  unsigned short* hhi0 = (unsigned short*)(ws);
  unsigned short* hhi1 = (unsigned short*)(ws + HB);
  unsigned short* hhi2 = (unsigned short*)(ws + 2 * HB);
  unsigned*       bar  = (unsigned*)(ws + 3 * HB);
  unsigned short* dummy = (unsigned short*)(ws + 3 * HB + 4096);  // unused lo

  hipMemsetAsync(bar, 0, 4096, stream);    // zero barrier/rendezvous counters

  (void)in_sizes; (void)n_in; (void)out_size; (void)ws_size;
  hipLaunchKernelGGL(lstm_persistent, dim3(GR * GP), dim3(512), 0, stream,
                     xin, h0, c0, Wi, bi, Wf, bfv, Wc, bc, Wo, bo,
                     Wout, bout, out, hhi0, hhi1, hhi2, dummy, dummy, dummy, bar);
}

// Round 13
// 683.792 us; speedup vs baseline: 1.8718x; 1.0272x over previous
//
#include <hip/hip_runtime.h>

typedef float f32x4 __attribute__((ext_vector_type(4)));
typedef short s16x8 __attribute__((ext_vector_type(8)));
typedef unsigned uint4v __attribute__((ext_vector_type(4)));

#define HH   768
#define HHP  776   // h-buffer row pitch in shorts (GLOBAL and LDS identical)
#define SS   256
#define GR   8     // row groups (16 rows each); g = blockIdx & 7
#define GP   24    // col blocks per group; p = blockIdx >> 3
#define NROW 128
#define LDP  776   // LDS row pitch (shorts); 1552B = 16B-aligned rows
#define PP   68    // partials row pitch (floats)

__device__ __forceinline__ unsigned short f2bf(float f) {
  unsigned int u = __float_as_uint(f);
  u += 0x7FFFu + ((u >> 16) & 1u);          // RTNE
  return (unsigned short)(u >> 16);
}
__device__ __forceinline__ float bf2f(unsigned short s) {
  return __uint_as_float(((unsigned int)s) << 16);
}
__device__ __forceinline__ float sigm(float v) { return 1.0f / (1.0f + __expf(-v)); }
__device__ __forceinline__ float tanhf_(float v) {
  return 1.0f - 2.0f / (__expf(2.0f * v) + 1.0f);
}
// async global->LDS, 16B per lane; dest = wave-uniform base + lane*16 (HW).
__device__ __forceinline__ void gll16(const void* gp, void* lp) {
  __builtin_amdgcn_global_load_lds(
      (const __attribute__((address_space(1))) unsigned*)gp,
      (__attribute__((address_space(3))) unsigned*)lp, 16, 0, 0);
}

// FINAL (R20 = byte-exact revert to R16, the best-measured variant:
// steady 624.5us, harness 680.6us, absmax 1.2e-4; baseline was 968us).
// 192 blocks x 512 threads (8 waves, 2/SIMD via launch_bounds(512,2)).
// Static roles: g = blockIdx&7 (rows [16g,16g+16)), p = blockIdx>>3 (hidden
// cols [32p,32p+32)); gate cols permuted col = hcol*4 + gate.
// Wave w: colh = w&1 (64-gate-col half), ks = w>>1 (6-kt slice of K).
// Win ledger: R12 (968->830) h transported bf16-only, W error compensated
// in-register; R15 (830->687, steady 624) W single-bf16 — 24 MFMA/wave,
// absmax unchanged 1.2e-4; R14/R16 (neutral, kept) gll16 DMA staging +
// register residency for bias/x-weight/c-state.
// Sync: R6-proven relay — per-step block-wide s_waitcnt(0) + __syncthreads,
// tid0 agent-scope fetch_add arrival + sleepless relaxed-load poll on ONE
// group counter, release __syncthreads. SIX structural variants failed
// (R8 flag-poll, R9 sc0-load poll hang, R13 RMW-poll +25%, R17 all-wave
// poll flood 2x, R18 sharded counters +25%, R19 LDS-relay arrival +2%):
// this relay is the empirical optimum for 24-block single-XCD consensus.
// Remaining step budget ~2350cy = data-dependency coherence chain
// (~1300-1500cy, irreducible per the 6 attempts) + staging latency
// (~500cy, off critical path) + MFMA 233cy + epilogue ~250cy.
// Transport: XCC_ID vote gating write-through stores + plain loads in the
// XCD L2 (3 parities defeat stale L1); slow path agent-scope (MALL) ops.
__global__ void __launch_bounds__(512, 2) lstm_persistent(
    const float* __restrict__ xin, const float* __restrict__ h0,
    const float* __restrict__ c0,
    const float* __restrict__ Wi, const float* __restrict__ bi,
    const float* __restrict__ Wf, const float* __restrict__ bfv,
    const float* __restrict__ Wc, const float* __restrict__ bc,
    const float* __restrict__ Wo, const float* __restrict__ bo,
    const float* __restrict__ Wout, const float* __restrict__ bout,
    float* __restrict__ out,
    unsigned short* __restrict__ hhi0, unsigned short* __restrict__ hhi1,
    unsigned short* __restrict__ hhi2,
    unsigned short* __restrict__ hlo0, unsigned short* __restrict__ hlo1,
    unsigned short* __restrict__ hlo2,
    unsigned* __restrict__ bar)
{
  const int tid = threadIdx.x, wave = tid >> 6, lane = tid & 63;
  const int l15 = lane & 15, quad = lane >> 4;
  const int g = blockIdx.x & 7, p = blockIdx.x >> 3;
  const int row_base = g * 16, hcol_base = p * 32;
  const int colh = wave & 1, ks = wave >> 1;   // col-half / kt-slice

  __shared__ __align__(16) unsigned short lds_hi[16 * LDP];
  __shared__ __align__(16) float part[2][4][16][PP];   // [colh][ks][row][col64]
  __shared__ float bw_b[128], bw_w[128];               // bias / x-weight per col
  __shared__ float c_lds[16][33];                      // init handoff only
  __shared__ float x_lds[16];
  __shared__ int s_fast;

  unsigned* ctr = bar + g * 64;              // step barrier (256B-spaced)
  unsigned* rdy = bar + 512 + g * 16;        // rendezvous counter
  unsigned* ids = bar + 640 + g * 32;        // 24 published XCC_IDs

  // ---- one-time vote (tid0): all 24 members on one XCD? [R6-proven] ----
  if (tid == 0) {
    const unsigned my = (__builtin_amdgcn_s_getreg(20 | (3 << 11)) & 15u) + 1u;
    __hip_atomic_store(ids + p, my, __ATOMIC_RELAXED, __HIP_MEMORY_SCOPE_AGENT);
    __hip_atomic_fetch_add(rdy, 1u, __ATOMIC_RELEASE, __HIP_MEMORY_SCOPE_AGENT);
    while (__hip_atomic_load(rdy, __ATOMIC_ACQUIRE, __HIP_MEMORY_SCOPE_AGENT)
           < (unsigned)GP)
      __builtin_amdgcn_s_sleep(8);
    int ok = 1;
    for (int q = 0; q < GP; ++q)
      ok &= (__hip_atomic_load(ids + q, __ATOMIC_RELAXED,
                               __HIP_MEMORY_SCOPE_AGENT) == my);
    s_fast = ok;
  }

  // ---- one-time: weights -> bf16 hi B-fragments (n=lane&15, k=quad*8+j) --
  s16x8 Bhi[6][4];
#pragma unroll
  for (int n = 0; n < 4; ++n) {
    const int col = p * 128 + colh * 64 + n * 16 + l15;  // permuted gate col
    const int gg = col & 3, hc = col >> 2;
    const float* W = (gg == 0) ? Wi : (gg == 1) ? Wf : (gg == 2) ? Wc : Wo;
#pragma unroll
    for (int ktl = 0; ktl < 6; ++ktl) {
      const int kt = ks * 6 + ktl;
      s16x8 vh;
#pragma unroll
      for (int j = 0; j < 8; ++j) {
        const int k = kt * 32 + quad * 8 + j;
        vh[j] = (short)f2bf(W[(1 + k) * HH + hc]);
      }
      Bhi[ktl][n] = vh;
    }
  }

  // ---- one-time: bias + x-weight tables -> LDS (per permuted gate col) ----
  if (tid < 128) {
    const int gg = tid & 3;
    const int hc = p * 32 + (tid >> 2);
    const float* W  = (gg == 0) ? Wi : (gg == 1) ? Wf : (gg == 2) ? Wc : Wo;
    const float* bb = (gg == 0) ? bi : (gg == 1) ? bfv : (gg == 2) ? bc : bo;
    bw_b[tid] = bb[hc];
    bw_w[tid] = W[hc];                       // W row 0 = x weight (exact fp32)
  }

  // ---- init: c->LDS; h0 -> parity-0 hi buffer (agent stores, pitch 776) --
  if (tid < 256) {
    const int lr = tid >> 4, lc = (tid & 15) * 2;
    const int gidx = (row_base + lr) * HH + hcol_base + lc;    // input (768)
    const int sidx = (row_base + lr) * HHP + hcol_base + lc;   // buffer (776)
    const float ha = h0[gidx], hb = h0[gidx + 1];
    c_lds[lr][lc]     = c0[gidx];
    c_lds[lr][lc + 1] = c0[gidx + 1];
    const unsigned short ha_hi = f2bf(ha), hb_hi = f2bf(hb);
    __hip_atomic_store((unsigned*)hhi0 + (sidx >> 1),
                       (unsigned)ha_hi | ((unsigned)hb_hi << 16),
                       __ATOMIC_RELAXED, __HIP_MEMORY_SCOPE_AGENT);
    if (tid < 16) {
      const int row = row_base + tid;
      x_lds[tid] = xin[(row >> 1) * (SS * 2) + (row & 1)];   // t = 0
    }
  }
  __syncthreads();                           // s_fast + LDS init visible
  const bool fast = (s_fast != 0);
  unsigned bars = 0;

  // Agent-scope counter barrier (R3/R6-proven relay; sleepless poll).
  auto gbar = [&]() {
    __builtin_amdgcn_s_waitcnt(0);
    __syncthreads();
    if (tid == 0) {
      ++bars;
      __hip_atomic_fetch_add(ctr, 1u, __ATOMIC_RELAXED, __HIP_MEMORY_SCOPE_AGENT);
      const unsigned want = (unsigned)GP * bars;
      while (__hip_atomic_load(ctr, __ATOMIC_RELAXED, __HIP_MEMORY_SCOPE_AGENT) < want) {}
    }
    __syncthreads();
  };

  // ---- hoisted loop invariants (compiler can't hoist across barriers) ----
  const int lr_c = tid >> 5, lc_c = tid & 31;        // elementwise cell
  const int ch_c = lc_c >> 4, c4_c = (lc_c & 15) * 4;
  const f32x4 bq = *(const f32x4*)&bw_b[lc_c * 4];   // bias (4 gates of cell)
  const f32x4 wq = *(const f32x4*)&bw_w[lc_c * 4];   // x-weight (4 gates)
  float cc_reg = c_lds[lr_c][lc_c];                  // c state in register

  gbar();                                    // h0/c0 published

  const unsigned short* hbhi[3] = {hhi0, hhi1, hhi2};
  unsigned short* wbhi[3] = {hhi0, hhi1, hhi2};

  const int frag_off = l15 * LDP + quad * 8; // A-frag LDS offset (shorts)
  const int wbase = wave * 64;               // wave-uniform lane base
  int cur = 0;

  for (int t = 0; t < SS; ++t) {
    const int nxt = (cur == 2) ? 0 : cur + 1;
    const unsigned short* rhi = hbhi[cur];
    unsigned short* whi = wbhi[nxt];

    // ---- stage group h-slice: identity copy 16 x 776 shorts (24832B) ----
    if (fast) {                              // async global->LDS, no VGPR trip
      const unsigned short* src = rhi + row_base * HHP;
#pragma unroll
      for (int i = 0; i < 3; ++i) {
        const int gi = i * 512 + tid;        // u128 idx (per-lane global src)
        gll16(src + gi * 8, &lds_hi[(i * 512 + wbase) * 8]);
      }
      if (tid < 16) {                        // tail u128s 1536..1551 (plain)
        const uint4v v = *(const uint4v*)(src + (1536 + tid) * 8);
        *(uint4v*)&lds_hi[(1536 + tid) * 8] = v;
      }
    } else {                                 // agent-scope (MALL) identity copy
      const unsigned long long* src64 =
          (const unsigned long long*)rhi + row_base * (HHP / 4);
#pragma unroll
      for (int i = 0; i < 6; ++i) {
        const int gi = i * 512 + tid;        // u64 idx in [0,3072)
        const unsigned long long vh = __hip_atomic_load(
            src64 + gi, __ATOMIC_RELAXED, __HIP_MEMORY_SCOPE_AGENT);
        *(unsigned long long*)&lds_hi[gi * 4] = vh;
      }
      if (tid < 32) {                        // tail u64s 3072..3103
        const int gi = 3072 + tid;
        const unsigned long long vh = __hip_atomic_load(
            src64 + gi, __ATOMIC_RELAXED, __HIP_MEMORY_SCOPE_AGENT);
        *(unsigned long long*)&lds_hi[gi * 4] = vh;
      }
    }
    __syncthreads();                         // drains vmcnt (gll) + lgkm

    // ---- GEMM: wave (colh,ks): 6kt x 4n, 1 MFMA/(ktl,n): h_hi*W_hi ----
    f32x4 acc[4] = {{0,0,0,0},{0,0,0,0},{0,0,0,0},{0,0,0,0}};
#pragma unroll
    for (int ktl = 0; ktl < 6; ++ktl) {
      const int kt = ks * 6 + ktl;
      const s16x8 ah = *(const s16x8*)&lds_hi[frag_off + kt * 32];
#pragma unroll
      for (int n = 0; n < 4; ++n)
        acc[n] = __builtin_amdgcn_mfma_f32_16x16x32_bf16(ah, Bhi[ktl][n], acc[n], 0, 0, 0);
    }

    // ---- partial write: C/D layout col=l15, row=quad*4+reg ----
#pragma unroll
    for (int n = 0; n < 4; ++n)
#pragma unroll
      for (int reg = 0; reg < 4; ++reg)
        part[colh][ks][quad * 4 + reg][n * 16 + l15] = acc[n][reg];
    __syncthreads();

    // ---- reduce over ks + bias + x*w0; elementwise; h store (1 cell/thr) --
    {
      const f32x4 s0 = *(const f32x4*)&part[ch_c][0][lr_c][c4_c];
      const f32x4 s1 = *(const f32x4*)&part[ch_c][1][lr_c][c4_c];
      const f32x4 s2 = *(const f32x4*)&part[ch_c][2][lr_c][c4_c];
      const f32x4 s3 = *(const f32x4*)&part[ch_c][3][lr_c][c4_c];
      const float xv = x_lds[lr_c];
      f32x4 gv = (s0 + s1) + (s2 + s3);
#pragma unroll
      for (int j = 0; j < 4; ++j) gv[j] += bq[j] + xv * wq[j];

      cc_reg = sigm(gv[1]) * cc_reg + sigm(gv[0]) * tanhf_(gv[2]);
      const float hh = gv[3] * tanhf_(cc_reg);  // no sigmoid on o-gate (ref)

      const unsigned short mhi = f2bf(hh);
      const unsigned ohi = (unsigned)__shfl_down((int)(unsigned)mhi, 1, 64);
      if ((tid & 1) == 0) {                  // lc_c even; neighbor = lc_c+1
        const int sidx = (row_base + lr_c) * HHP + hcol_base + lc_c;
        const unsigned ph = (unsigned)mhi | (ohi << 16);
        if (fast) {                          // write-through L1 -> XCD L2
          ((unsigned*)whi)[sidx >> 1] = ph;
        } else {
          __hip_atomic_store((unsigned*)whi + (sidx >> 1), ph, __ATOMIC_RELAXED, __HIP_MEMORY_SCOPE_AGENT);
        }
      }
      if (tid < 16 && t + 1 < SS) {
        const int row = row_base + tid;
        x_lds[tid] = xin[(row >> 1) * (SS * 2) + (t + 1) * 2 + (row & 1)];
      }
    }
    gbar();
    cur = nxt;
  }

  // ---- output projection: final h in parity cur = 256%3 = 1 ----
  if (p == 0 && tid < 256) {
    const unsigned short* fhi = hbhi[cur];
    const int rloc = tid >> 4, s = tid & 15;
    const int row = row_base + rloc;
    float sum = 0.0f;
#pragma unroll
    for (int i = 0; i < 12; ++i) {
      const int u = row * (HHP / 4) + s * 12 + i;  // u64 idx; k0 = s*48 + i*4
      unsigned long long vh;
      if (fast) {                            // fresh in this XCD's L2
        vh = *((const unsigned long long*)fhi + u);
      } else {
        vh = __hip_atomic_load((unsigned long long*)fhi + u, __ATOMIC_RELAXED, __HIP_MEMORY_SCOPE_AGENT);
      }
#pragma unroll
      for (int j = 0; j < 4; ++j) {
        const float h = bf2f((unsigned short)(vh >> (16 * j)));
        sum += h * Wout[s * 48 + i * 4 + j];
      }
    }
#pragma unroll
    for (int off = 8; off; off >>= 1) sum += __shfl_down(sum, off, 16);
    if (s == 0) out[row] = sum + bout[0];
  }
}

extern "C" void kernel_launch(void* const* d_in, const int* in_sizes, int n_in,
                              void* d_out, int out_size, void* d_ws, size_t ws_size,
                              hipStream_t stream) {
  const float* xin  = (const float*)d_in[0];
  const float* h0   = (const float*)d_in[1];
  const float* c0   = (const float*)d_in[2];
  const float* Wi   = (const float*)d_in[3];
  const float* bi   = (const float*)d_in[4];
  const float* Wf   = (const float*)d_in[5];
  const float* bfv  = (const float*)d_in[6];
  const float* Wc   = (const float*)d_in[7];
  const float* bc   = (const float*)d_in[8];
  const float* Wo   = (const float*)d_in[9];
  const float* bo   = (const float*)d_in[10];
  const float* Wout = (const float*)d_in[11];
  const float* bout = (const float*)d_in[12];
  float* out = (float*)d_out;

  char* ws = (char*)d_ws;
  const size_t HB = (size_t)NROW * HHP * sizeof(unsigned short);  // 198656
  unsigned short* hhi0 = (unsigned short*)(ws);
  unsigned short* hhi1 = (unsigned short*)(ws + HB);
  unsigned short* hhi2 = (unsigned short*)(ws + 2 * HB);
  unsigned*       bar  = (unsigned*)(ws + 3 * HB);
  unsigned short* dummy = (unsigned short*)(ws + 3 * HB + 4096);  // unused lo

  hipMemsetAsync(bar, 0, 4096, stream);    // zero barrier/rendezvous counters

  (void)in_sizes; (void)n_in; (void)out_size; (void)ws_size;
  hipLaunchKernelGGL(lstm_persistent, dim3(GR * GP), dim3(512), 0, stream,
                     xin, h0, c0, Wi, bi, Wf, bfv, Wc, bc, Wo, bo,
                     Wout, bout, out, hhi0, hhi1, hhi2, dummy, dummy, dummy, bar);
}